// Round 4
// baseline (142.940 us; speedup 1.0000x reference)
//
#include <hip/hip_runtime.h>
#include <hip/hip_bf16.h>

typedef float  f32x4  __attribute__((ext_vector_type(4)));
typedef short  bf16x8 __attribute__((ext_vector_type(8)));

#define Bsz  8192
#define Dsz  64
#define Hsz  128
#define Tsz  41
#define ROWS 16
#define NT   256

#define MFMA(a,b,c) __builtin_amdgcn_mfma_f32_16x16x32_bf16((a),(b),(c),0,0,0)

__device__ __forceinline__ float fast_tanh(float x) {
    float ax = __builtin_fabsf(x);
    float e  = __expf(-2.0f * ax);
    float r  = (1.0f - e) * __builtin_amdgcn_rcpf(1.0f + e);
    return __builtin_copysignf(r, x);
}

__device__ __forceinline__ unsigned short bf2u(__hip_bfloat16 h) {
    union { __hip_bfloat16 b; unsigned short u; } v; v.b = h; return v.u;
}

union FragU { bf16x8 f; unsigned short h[8]; };

// split 8 f32 into hi/lo bf16 fragments (elem i at position i)
__device__ __forceinline__ void split8(const float* x, bf16x8& hi, bf16x8& lo) {
    FragU H, L;
    #pragma unroll
    for (int i = 0; i < 8; ++i) {
        __hip_bfloat16 hb = __float2bfloat16(x[i]);
        H.h[i] = bf2u(hb);
        L.h[i] = bf2u(__float2bfloat16(x[i] - __bfloat162float(hb)));
    }
    hi = H.f; lo = L.f;
}

__device__ __forceinline__ bf16x8 ldb128(const unsigned short* base, int byteoff) {
    return *(const bf16x8*)((const char*)base + byteoff);
}
__device__ __forceinline__ void stb16(unsigned short* base, int byteoff, unsigned short v) {
    *(unsigned short*)((char*)base + byteoff) = v;
}

__global__ __launch_bounds__(NT, 2)
void ode_mfma4(const float* __restrict__ z0, const float* __restrict__ t,
               const float* __restrict__ W1, const float* __restrict__ b1,
               const float* __restrict__ W2, const float* __restrict__ b2,
               float* __restrict__ out)
{
    // double-buffered activation H/L tiles, [buf][row][h], XOR-swizzled bytes
    __shared__ __align__(16) unsigned short aHs[2][ROWS * Hsz];
    __shared__ __align__(16) unsigned short aLs[2][ROWS * Hsz];
    __shared__ float ts[Tsz];

    const int tid  = threadIdx.x;
    const int lane = tid & 63;
    const int w    = tid >> 6;   // wave: layer1 owns h-cols w*32..w*32+31
    const int g    = lane >> 4;
    const int c    = lane & 15;
    const int r0   = blockIdx.x * ROWS;

    if (tid < Tsz) ts[tid] = t[tid];

    // ---- z master fully in registers: zr[mt][reg] = z[row=c][d=16mt+4g+reg] ----
    f32x4 zr[4];
    #pragma unroll
    for (int mt = 0; mt < 4; ++mt)
        #pragma unroll
        for (int reg = 0; reg < 4; ++reg)
            zr[mt][reg] = z0[(r0 + c) * Dsz + (16*mt + 4*g + reg)];

    // ---- W1 B-fragments (wave's 32 h-cols), k relabeled by kappa ----
    // kappa(32kt+8g+i) = 16*(2kt + (i>>2)) + 4g + (i&3)
    bf16x8 w1h[2][2], w1l[2][2];   // [nt][kt]
    #pragma unroll
    for (int nt = 0; nt < 2; ++nt) {
        const int n = w*32 + nt*16 + c;
        #pragma unroll
        for (int kt = 0; kt < 2; ++kt) {
            float tmp[8];
            #pragma unroll
            for (int i = 0; i < 8; ++i) {
                int d = 16*(2*kt + (i >> 2)) + 4*g + (i & 3);
                tmp[i] = W1[d * Hsz + n];
            }
            split8(tmp, w1h[nt][kt], w1l[nt][kt]);
        }
    }
    // ---- W2^T A-fragments, FULL d=64 per wave (redundant across waves) ----
    // lane holds A[row=16mt+c][k=32kt2+8g+i] = W2[32kt2+8g+i][16mt+c]
    bf16x8 w2h[4][4], w2l[4][4];   // [mt][kt2]
    #pragma unroll
    for (int mt = 0; mt < 4; ++mt) {
        const int dcol = 16*mt + c;
        #pragma unroll
        for (int kt2 = 0; kt2 < 4; ++kt2) {
            float tmp[8];
            #pragma unroll
            for (int i = 0; i < 8; ++i)
                tmp[i] = W2[(32*kt2 + 8*g + i) * Dsz + dcol];
            split8(tmp, w2h[mt][kt2], w2l[mt][kt2]);
        }
    }
    const float b1r[2] = { b1[w*32 + c], b1[w*32 + 16 + c] };
    f32x4 b2v[4];
    #pragma unroll
    for (int mt = 0; mt < 4; ++mt)
        #pragma unroll
        for (int reg = 0; reg < 4; ++reg)
            b2v[mt][reg] = b2[16*mt + 4*g + reg];

    // ---- loop-invariant swizzled LDS byte offsets ----
    int awr[2][4];   // a-writes: rows 4g+reg, col w*32+nt*16+c
    #pragma unroll
    for (int reg = 0; reg < 4; ++reg) {
        const int row = 4*g + reg;
        #pragma unroll
        for (int nt = 0; nt < 2; ++nt)
            awr[nt][reg] = (row*256 + (w*32 + nt*16 + c)*2) ^ ((row & 7) << 4);
    }
    int ard[4];      // a-reads: row c, h = 32*kt2 + 8g .. +7
    #pragma unroll
    for (int kt2 = 0; kt2 < 4; ++kt2)
        ard[kt2] = (c*256 + kt2*64 + g*16) ^ ((c & 7) << 4);

    __syncthreads();

    const int n_steps = (int)ceilf(fabsf(ts[1] - ts[0]) / 0.05f);   // = 2

    int bs = 0;
    for (int iv = 0; iv < Tsz - 1; ++iv) {
        const float h = (ts[iv + 1] - ts[iv]) / (float)n_steps;
        for (int s = 0; s < n_steps; ++s) {
            // ---- z -> A-frags (pure VALU, kappa ordering = concat zr rows 2kt,2kt+1)
            bf16x8 zh[2], zl[2];
            #pragma unroll
            for (int kt = 0; kt < 2; ++kt) {
                float tmp[8];
                *(f32x4*)&tmp[0] = zr[2*kt];
                *(f32x4*)&tmp[4] = zr[2*kt + 1];
                split8(tmp, zh[kt], zl[kt]);
            }
            // ---- layer 1: a = tanh(z @ W1 + b1), write H/L to LDS buf bs ----
            unsigned short* aH = aHs[bs];
            unsigned short* aL = aLs[bs];
            #pragma unroll
            for (int nt = 0; nt < 2; ++nt) {
                f32x4 acc = { b1r[nt], b1r[nt], b1r[nt], b1r[nt] };
                acc = MFMA(zh[0], w1h[nt][0], acc);
                acc = MFMA(zh[1], w1h[nt][1], acc);
                acc = MFMA(zh[0], w1l[nt][0], acc);
                acc = MFMA(zh[1], w1l[nt][1], acc);
                acc = MFMA(zl[0], w1h[nt][0], acc);
                acc = MFMA(zl[1], w1h[nt][1], acc);
                #pragma unroll
                for (int reg = 0; reg < 4; ++reg) {
                    float a = fast_tanh(acc[reg]);
                    __hip_bfloat16 hb = __float2bfloat16(a);
                    stb16(aH, awr[nt][reg], bf2u(hb));
                    stb16(aL, awr[nt][reg],
                          bf2u(__float2bfloat16(a - __bfloat162float(hb))));
                }
            }
            __syncthreads();
            // ---- layer 2 (transposed, full d per wave): dz^T = W2^T @ a^T ----
            f32x4 acc2[4] = { b2v[0], b2v[1], b2v[2], b2v[3] };
            #pragma unroll
            for (int kt2 = 0; kt2 < 4; ++kt2) {
                bf16x8 ah = ldb128(aH, ard[kt2]);
                bf16x8 al = ldb128(aL, ard[kt2]);
                #pragma unroll
                for (int mt = 0; mt < 4; ++mt)
                    acc2[mt] = MFMA(w2h[mt][kt2], ah, acc2[mt]);
                #pragma unroll
                for (int mt = 0; mt < 4; ++mt)
                    acc2[mt] = MFMA(w2l[mt][kt2], ah, acc2[mt]);
                #pragma unroll
                for (int mt = 0; mt < 4; ++mt)
                    acc2[mt] = MFMA(w2h[mt][kt2], al, acc2[mt]);
            }
            // ---- z += h * dz (pure register update; C-layout matches zr) ----
            #pragma unroll
            for (int mt = 0; mt < 4; ++mt)
                zr[mt] += h * acc2[mt];
            bs ^= 1;
        }
    }

    // ---- write result ----
    #pragma unroll
    for (int mt = 0; mt < 4; ++mt)
        #pragma unroll
        for (int reg = 0; reg < 4; ++reg)
            out[(r0 + c) * Dsz + (16*mt + 4*g + reg)] = zr[mt][reg];
}

extern "C" void kernel_launch(void* const* d_in, const int* in_sizes, int n_in,
                              void* d_out, int out_size, void* d_ws, size_t ws_size,
                              hipStream_t stream) {
    const float* z0 = (const float*)d_in[0];
    const float* t  = (const float*)d_in[1];
    const float* W1 = (const float*)d_in[2];
    const float* b1 = (const float*)d_in[3];
    const float* W2 = (const float*)d_in[4];
    const float* b2 = (const float*)d_in[5];
    float* out = (float*)d_out;
    (void)in_sizes; (void)n_in; (void)out_size; (void)d_ws; (void)ws_size;

    ode_mfma4<<<dim3(Bsz / ROWS), dim3(NT), 0, stream>>>(z0, t, W1, b1, W2, b2, out);
}

// Round 5
// 114.714 us; speedup vs baseline: 1.2461x; 1.2461x over previous
//
#include <hip/hip_runtime.h>
#include <hip/hip_bf16.h>

typedef float    f32x4  __attribute__((ext_vector_type(4)));
typedef short    bf16x8 __attribute__((ext_vector_type(8)));
typedef unsigned u32x4  __attribute__((ext_vector_type(4)));

#define Bsz  8192
#define Dsz  64
#define Hsz  128
#define Tsz  41
#define ROWS 16
#define NT   256

#define MFMA(a,b,c) __builtin_amdgcn_mfma_f32_16x16x32_bf16((a),(b),(c),0,0,0)

__device__ __forceinline__ float fast_tanh(float x) {
    float ax = __builtin_fabsf(x);
    float e  = __expf(-2.0f * ax);
    float r  = (1.0f - e) * __builtin_amdgcn_rcpf(1.0f + e);
    return __builtin_copysignf(r, x);
}

__device__ __forceinline__ unsigned short bf2u(__hip_bfloat16 h) {
    union { __hip_bfloat16 b; unsigned short u; } v; v.b = h; return v.u;
}

// pack f32 -> (H bf16 low16) | (L bf16 high16), L = bf16(x - f32(H))
__device__ __forceinline__ unsigned packHL(float x) {
    unsigned H = bf2u(__float2bfloat16(x));
    float hf = __uint_as_float(H << 16);
    unsigned L = bf2u(__float2bfloat16(x - hf));
    return H | (L << 16);
}

union FragU { bf16x8 f; unsigned short h[8]; };

// weight split (init only)
__device__ __forceinline__ void split8(const float* x, bf16x8& hi, bf16x8& lo) {
    FragU H, L;
    #pragma unroll
    for (int i = 0; i < 8; ++i) {
        __hip_bfloat16 hb = __float2bfloat16(x[i]);
        H.h[i] = bf2u(hb);
        L.h[i] = bf2u(__float2bfloat16(x[i] - __bfloat162float(hb)));
    }
    hi = H.f; lo = L.f;
}

// read 8 packed dwords (two b128) and v_perm-unpack into hi/lo bf16x8 frags
__device__ __forceinline__ void mk_frags(const unsigned* base, int off0, int off1,
                                         bf16x8& hi, bf16x8& lo) {
    u32x4 qa = *(const u32x4*)((const char*)base + off0);
    u32x4 qb = *(const u32x4*)((const char*)base + off1);
    union { bf16x8 f; unsigned u[4]; } H, L;
    H.u[0] = __builtin_amdgcn_perm(qa[1], qa[0], 0x05040100u);
    L.u[0] = __builtin_amdgcn_perm(qa[1], qa[0], 0x07060302u);
    H.u[1] = __builtin_amdgcn_perm(qa[3], qa[2], 0x05040100u);
    L.u[1] = __builtin_amdgcn_perm(qa[3], qa[2], 0x07060302u);
    H.u[2] = __builtin_amdgcn_perm(qb[1], qb[0], 0x05040100u);
    L.u[2] = __builtin_amdgcn_perm(qb[1], qb[0], 0x07060302u);
    H.u[3] = __builtin_amdgcn_perm(qb[3], qb[2], 0x05040100u);
    L.u[3] = __builtin_amdgcn_perm(qb[3], qb[2], 0x07060302u);
    hi = H.f; lo = L.f;
}

__device__ __forceinline__ void stu32(unsigned* base, int byteoff, unsigned v) {
    *(unsigned*)((char*)base + byteoff) = v;
}

__global__ __launch_bounds__(NT, 2)
void ode_mfma5(const float* __restrict__ z0, const float* __restrict__ t,
               const float* __restrict__ W1, const float* __restrict__ b1,
               const float* __restrict__ W2, const float* __restrict__ b2,
               float* __restrict__ out)
{
    __shared__ unsigned zP[ROWS * Dsz];   // packed H|L, [row][d], XOR-swizzled bytes
    __shared__ unsigned aP[ROWS * Hsz];   // packed H|L, [row][h], XOR-swizzled bytes
    __shared__ float ts[Tsz];

    const int tid  = threadIdx.x;
    const int lane = tid & 63;
    const int w    = tid >> 6;   // wave: layer1 h-cols w*32..+31, layer2 d-cols w*16..+15
    const int g    = lane >> 4;
    const int c    = lane & 15;
    const int r0   = blockIdx.x * ROWS;

    if (tid < Tsz) ts[tid] = t[tid];

    // ---- z master in registers (layer2 C layout): zreg[reg] = z[4g+reg][w*16+c] ----
    float zreg[4];
    #pragma unroll
    for (int reg = 0; reg < 4; ++reg)
        zreg[reg] = z0[(r0 + 4*g + reg) * Dsz + (w*16 + c)];

    // ---- loop-invariant weight B-fragments (hi/lo split) ----
    bf16x8 w1h[2][2], w1l[2][2];   // [nt][kt]
    #pragma unroll
    for (int nt = 0; nt < 2; ++nt) {
        const int n = w*32 + nt*16 + c;
        #pragma unroll
        for (int kt = 0; kt < 2; ++kt) {
            float tmp[8];
            #pragma unroll
            for (int i = 0; i < 8; ++i) tmp[i] = W1[(kt*32 + g*8 + i) * Hsz + n];
            split8(tmp, w1h[nt][kt], w1l[nt][kt]);
        }
    }
    bf16x8 w2h[4], w2l[4];         // [kt2]
    {
        const int n = w*16 + c;
        #pragma unroll
        for (int kt2 = 0; kt2 < 4; ++kt2) {
            float tmp[8];
            #pragma unroll
            for (int i = 0; i < 8; ++i) tmp[i] = W2[(kt2*32 + g*8 + i) * Dsz + n];
            split8(tmp, w2h[kt2], w2l[kt2]);
        }
    }
    const float b1r[2] = { b1[w*32 + c], b1[w*32 + 16 + c] };
    const float b2r    = b2[w*16 + c];

    // ---- loop-invariant swizzled LDS byte offsets ----
    int zw[4], aw[2][4];
    #pragma unroll
    for (int reg = 0; reg < 4; ++reg) {
        const int row = 4*g + reg;
        zw[reg] = (row*256 + (w*16 + c)*4) ^ ((row & 7) << 4);
        #pragma unroll
        for (int nt = 0; nt < 2; ++nt)
            aw[nt][reg] = (row*512 + (w*32 + nt*16 + c)*4) ^ ((row & 7) << 4);
    }
    int zr[2][2], ar[4][2];
    #pragma unroll
    for (int kt = 0; kt < 2; ++kt) {
        const int base = c*256 + (kt*32 + 8*g)*4;
        zr[kt][0] = base ^ ((c & 7) << 4);
        zr[kt][1] = (base + 16) ^ ((c & 7) << 4);
    }
    #pragma unroll
    for (int kt2 = 0; kt2 < 4; ++kt2) {
        const int base = c*512 + (kt2*32 + 8*g)*4;
        ar[kt2][0] = base ^ ((c & 7) << 4);
        ar[kt2][1] = (base + 16) ^ ((c & 7) << 4);
    }

    // initial z -> LDS (packed)
    #pragma unroll
    for (int reg = 0; reg < 4; ++reg) stu32(zP, zw[reg], packHL(zreg[reg]));
    __syncthreads();

    const int n_steps = (int)ceilf(fabsf(ts[1] - ts[0]) / 0.05f);   // = 2

    for (int iv = 0; iv < Tsz - 1; ++iv) {
        const float h = (ts[iv + 1] - ts[iv]) / (float)n_steps;
        for (int s = 0; s < n_steps; ++s) {
            // ---- layer 1: 6 independent 2-deep MFMA chains ----
            bf16x8 zh0, zl0, zh1, zl1;
            mk_frags(zP, zr[0][0], zr[0][1], zh0, zl0);
            mk_frags(zP, zr[1][0], zr[1][1], zh1, zl1);
            f32x4 cA0 = { b1r[0], b1r[0], b1r[0], b1r[0] };
            f32x4 cA1 = { b1r[1], b1r[1], b1r[1], b1r[1] };
            f32x4 cB0 = {0,0,0,0}, cB1 = {0,0,0,0}, cC0 = {0,0,0,0}, cC1 = {0,0,0,0};
            cA0 = MFMA(zh0, w1h[0][0], cA0);  cA1 = MFMA(zh0, w1h[1][0], cA1);
            cB0 = MFMA(zh0, w1l[0][0], cB0);  cB1 = MFMA(zh0, w1l[1][0], cB1);
            cC0 = MFMA(zl0, w1h[0][0], cC0);  cC1 = MFMA(zl0, w1h[1][0], cC1);
            cA0 = MFMA(zh1, w1h[0][1], cA0);  cA1 = MFMA(zh1, w1h[1][1], cA1);
            cB0 = MFMA(zh1, w1l[0][1], cB0);  cB1 = MFMA(zh1, w1l[1][1], cB1);
            cC0 = MFMA(zl1, w1h[0][1], cC0);  cC1 = MFMA(zl1, w1h[1][1], cC1);
            f32x4 acc0 = (cA0 + cB0) + cC0;
            f32x4 acc1 = (cA1 + cB1) + cC1;
            #pragma unroll
            for (int reg = 0; reg < 4; ++reg) {
                stu32(aP, aw[0][reg], packHL(fast_tanh(acc0[reg])));
                stu32(aP, aw[1][reg], packHL(fast_tanh(acc1[reg])));
            }
            __syncthreads();
            // ---- layer 2: 6 independent 2-deep MFMA chains ----
            bf16x8 ah0, al0, ah1, al1, ah2, al2, ah3, al3;
            mk_frags(aP, ar[0][0], ar[0][1], ah0, al0);
            mk_frags(aP, ar[1][0], ar[1][1], ah1, al1);
            mk_frags(aP, ar[2][0], ar[2][1], ah2, al2);
            mk_frags(aP, ar[3][0], ar[3][1], ah3, al3);
            f32x4 d0 = { b2r, b2r, b2r, b2r };
            f32x4 d1 = {0,0,0,0}, d2 = {0,0,0,0}, d3 = {0,0,0,0}, d4 = {0,0,0,0}, d5 = {0,0,0,0};
            d0 = MFMA(ah0, w2h[0], d0);  d1 = MFMA(ah2, w2h[2], d1);
            d2 = MFMA(ah0, w2l[0], d2);  d3 = MFMA(ah2, w2l[2], d3);
            d4 = MFMA(al0, w2h[0], d4);  d5 = MFMA(al2, w2h[2], d5);
            d0 = MFMA(ah1, w2h[1], d0);  d1 = MFMA(ah3, w2h[3], d1);
            d2 = MFMA(ah1, w2l[1], d2);  d3 = MFMA(ah3, w2l[3], d3);
            d4 = MFMA(al1, w2h[1], d4);  d5 = MFMA(al3, w2h[3], d5);
            f32x4 dz = ((d0 + d1) + (d2 + d3)) + (d4 + d5);
            #pragma unroll
            for (int reg = 0; reg < 4; ++reg) {
                zreg[reg] += h * dz[reg];
                stu32(zP, zw[reg], packHL(zreg[reg]));
            }
            __syncthreads();
        }
    }

    #pragma unroll
    for (int reg = 0; reg < 4; ++reg)
        out[(r0 + 4*g + reg) * Dsz + (w*16 + c)] = zreg[reg];
}

extern "C" void kernel_launch(void* const* d_in, const int* in_sizes, int n_in,
                              void* d_out, int out_size, void* d_ws, size_t ws_size,
                              hipStream_t stream) {
    const float* z0 = (const float*)d_in[0];
    const float* t  = (const float*)d_in[1];
    const float* W1 = (const float*)d_in[2];
    const float* b1 = (const float*)d_in[3];
    const float* W2 = (const float*)d_in[4];
    const float* b2 = (const float*)d_in[5];
    float* out = (float*)d_out;
    (void)in_sizes; (void)n_in; (void)out_size; (void)d_ws; (void)ws_size;

    ode_mfma5<<<dim3(Bsz / ROWS), dim3(NT), 0, stream>>>(z0, t, W1, b1, W2, b2, out);
}

// Round 6
// 88.465 us; speedup vs baseline: 1.6158x; 1.2967x over previous
//
#include <hip/hip_runtime.h>
#include <hip/hip_bf16.h>

typedef float          f32x4  __attribute__((ext_vector_type(4)));
typedef short          bf16x8 __attribute__((ext_vector_type(8)));
typedef unsigned short u16x4  __attribute__((ext_vector_type(4)));

#define Bsz  8192
#define Dsz  64
#define Hsz  128
#define Tsz  41
#define ROWS 16
#define NT   256

#define MFMA(a,b,c) __builtin_amdgcn_mfma_f32_16x16x32_bf16((a),(b),(c),0,0,0)

__device__ __forceinline__ float fast_tanh(float x) {
    float ax = __builtin_fabsf(x);
    float e  = __expf(-2.0f * ax);
    float r  = (1.0f - e) * __builtin_amdgcn_rcpf(1.0f + e);
    return __builtin_copysignf(r, x);
}

__device__ __forceinline__ unsigned short bf2u(__hip_bfloat16 h) {
    union { __hip_bfloat16 b; unsigned short u; } v; v.b = h; return v.u;
}

union FragU { bf16x8 f; unsigned short h[8]; };

// split 8 f32 into hi/lo bf16 fragments (weights, init only)
__device__ __forceinline__ void split8(const float* x, bf16x8& hi, bf16x8& lo) {
    FragU H, L;
    #pragma unroll
    for (int i = 0; i < 8; ++i) {
        __hip_bfloat16 hb = __float2bfloat16(x[i]);
        H.h[i] = bf2u(hb);
        L.h[i] = bf2u(__float2bfloat16(x[i] - __bfloat162float(hb)));
    }
    hi = H.f; lo = L.f;
}

// split an f32x4 into H/L bf16 quads (for one b64 store each)
__device__ __forceinline__ void splitq(const f32x4& x, u16x4& H, u16x4& L) {
    #pragma unroll
    for (int i = 0; i < 4; ++i) {
        __hip_bfloat16 hb = __float2bfloat16(x[i]);
        H[i] = bf2u(hb);
        L[i] = bf2u(__float2bfloat16(x[i] - __bfloat162float(hb)));
    }
}

__device__ __forceinline__ bf16x8 ldb128(const unsigned short* base, int byteoff) {
    return *(const bf16x8*)((const char*)base + byteoff);
}
__device__ __forceinline__ void stb64(unsigned short* base, int byteoff, u16x4 v) {
    *(u16x4*)((char*)base + byteoff) = v;
}

__global__ __launch_bounds__(NT, 2)
void ode_mfma6(const float* __restrict__ z0, const float* __restrict__ t,
               const float* __restrict__ W1, const float* __restrict__ b1,
               const float* __restrict__ W2, const float* __restrict__ b2,
               float* __restrict__ out)
{
    // bf16 H/L tiles, [batch_row][feature], byte-index XOR-swizzled by (row&7)<<4
    __shared__ __align__(16) unsigned short zHs[ROWS * Dsz], zLs[ROWS * Dsz];
    __shared__ __align__(16) unsigned short aHs[ROWS * Hsz], aLs[ROWS * Hsz];
    __shared__ float ts[Tsz];

    const int tid  = threadIdx.x;
    const int lane = tid & 63;
    const int w    = tid >> 6;   // wave: layer1 h-cols 32w..+31, layer2 d-cols 16w..+15
    const int g    = lane >> 4;
    const int c    = lane & 15;  // batch row within tile
    const int r0   = blockIdx.x * ROWS;

    if (tid < Tsz) ts[tid] = t[tid];

    // ---- z master in registers (transposed layer2 D layout):
    //      zreg[reg] = z[batch=c][d = 16w + 4g + reg]  -> one dwordx4 ----
    f32x4 zreg = *(const f32x4*)&z0[(r0 + c) * Dsz + 16*w + 4*g];

    // ---- W1^T A-fragments: lane holds W1T[h=16(2w+nt)+c][d=32kt+8g+i] ----
    bf16x8 w1tH[2][2], w1tL[2][2];   // [nt][kt]
    #pragma unroll
    for (int nt = 0; nt < 2; ++nt) {
        const int n = 32*w + 16*nt + c;
        #pragma unroll
        for (int kt = 0; kt < 2; ++kt) {
            float tmp[8];
            #pragma unroll
            for (int i = 0; i < 8; ++i) tmp[i] = W1[(32*kt + 8*g + i) * Hsz + n];
            split8(tmp, w1tH[nt][kt], w1tL[nt][kt]);
        }
    }
    // ---- W2^T A-fragments: lane holds W2T[d=16w+c][h=32kt2+8g+i] ----
    bf16x8 w2tH[4], w2tL[4];         // [kt2]
    {
        const int n = 16*w + c;
        #pragma unroll
        for (int kt2 = 0; kt2 < 4; ++kt2) {
            float tmp[8];
            #pragma unroll
            for (int i = 0; i < 8; ++i) tmp[i] = W2[(32*kt2 + 8*g + i) * Dsz + n];
            split8(tmp, w2tH[kt2], w2tL[kt2]);
        }
    }
    // biases along the transposed D rows (4 consecutive features per lane)
    f32x4 b1v[2], b2v;
    #pragma unroll
    for (int nt = 0; nt < 2; ++nt)
        #pragma unroll
        for (int reg = 0; reg < 4; ++reg)
            b1v[nt][reg] = b1[16*(2*w + nt) + 4*g + reg];
    #pragma unroll
    for (int reg = 0; reg < 4; ++reg) b2v[reg] = b2[16*w + 4*g + reg];

    // ---- loop-invariant swizzled LDS byte offsets ----
    const int zw = (c*128 + (16*w + 4*g)*2) ^ ((c & 7) << 4);          // b64 write
    int zrd[2], aw[2], ard[4];
    #pragma unroll
    for (int kt = 0; kt < 2; ++kt)
        zrd[kt] = (c*128 + (32*kt + 8*g)*2) ^ ((c & 7) << 4);          // b128 read
    #pragma unroll
    for (int nt = 0; nt < 2; ++nt)
        aw[nt] = (c*256 + (32*w + 16*nt + 4*g)*2) ^ ((c & 7) << 4);    // b64 write
    #pragma unroll
    for (int kt2 = 0; kt2 < 4; ++kt2)
        ard[kt2] = (c*256 + (32*kt2 + 8*g)*2) ^ ((c & 7) << 4);        // b128 read

    auto z_to_lds = [&]() {
        u16x4 H, L;
        splitq(zreg, H, L);
        stb64(zHs, zw, H);
        stb64(zLs, zw, L);
    };

    z_to_lds();
    __syncthreads();

    const int n_steps = (int)ceilf(fabsf(ts[1] - ts[0]) / 0.05f);   // = 2 (exact in f32)

    for (int iv = 0; iv < Tsz - 1; ++iv) {
        const float h = (ts[iv + 1] - ts[iv]) / (float)n_steps;
        for (int s = 0; s < n_steps; ++s) {
            // ---- layer 1 (transposed): a^T = tanh(W1^T @ z^T + b1) ----
            bf16x8 zh0 = ldb128(zHs, zrd[0]), zh1 = ldb128(zHs, zrd[1]);
            bf16x8 zl0 = ldb128(zLs, zrd[0]), zl1 = ldb128(zLs, zrd[1]);
            #pragma unroll
            for (int nt = 0; nt < 2; ++nt) {
                f32x4 aA = b1v[nt];
                f32x4 aB = {0,0,0,0}, aC = {0,0,0,0};
                aA = MFMA(w1tH[nt][0], zh0, aA);
                aB = MFMA(w1tH[nt][0], zl0, aB);
                aC = MFMA(w1tL[nt][0], zh0, aC);
                aA = MFMA(w1tH[nt][1], zh1, aA);
                aB = MFMA(w1tH[nt][1], zl1, aB);
                aC = MFMA(w1tL[nt][1], zh1, aC);
                f32x4 av = (aA + aB) + aC;
                f32x4 tv;
                #pragma unroll
                for (int reg = 0; reg < 4; ++reg) tv[reg] = fast_tanh(av[reg]);
                u16x4 H, L;
                splitq(tv, H, L);
                stb64(aHs, aw[nt], H);    // lane holds 4 consecutive h -> one b64
                stb64(aLs, aw[nt], L);
            }
            __syncthreads();
            // ---- layer 2 (transposed): dz^T = W2^T @ a^T + b2 ----
            bf16x8 ah0 = ldb128(aHs, ard[0]), ah1 = ldb128(aHs, ard[1]);
            bf16x8 ah2 = ldb128(aHs, ard[2]), ah3 = ldb128(aHs, ard[3]);
            bf16x8 al0 = ldb128(aLs, ard[0]), al1 = ldb128(aLs, ard[1]);
            bf16x8 al2 = ldb128(aLs, ard[2]), al3 = ldb128(aLs, ard[3]);
            f32x4 dA = b2v;
            f32x4 dB = {0,0,0,0}, dC = {0,0,0,0};
            dA = MFMA(w2tH[0], ah0, dA);
            dB = MFMA(w2tH[0], al0, dB);
            dC = MFMA(w2tL[0], ah0, dC);
            dA = MFMA(w2tH[1], ah1, dA);
            dB = MFMA(w2tH[1], al1, dB);
            dC = MFMA(w2tL[1], ah1, dC);
            dA = MFMA(w2tH[2], ah2, dA);
            dB = MFMA(w2tH[2], al2, dB);
            dC = MFMA(w2tL[2], ah2, dC);
            dA = MFMA(w2tH[3], ah3, dA);
            dB = MFMA(w2tH[3], al3, dB);
            dC = MFMA(w2tL[3], ah3, dC);
            f32x4 dz = (dA + dB) + dC;
            zreg += h * dz;
            z_to_lds();                  // 2 b64 writes
            __syncthreads();
        }
    }

    // ---- write result (one dwordx4 per lane) ----
    *(f32x4*)&out[(r0 + c) * Dsz + 16*w + 4*g] = zreg;
}

extern "C" void kernel_launch(void* const* d_in, const int* in_sizes, int n_in,
                              void* d_out, int out_size, void* d_ws, size_t ws_size,
                              hipStream_t stream) {
    const float* z0 = (const float*)d_in[0];
    const float* t  = (const float*)d_in[1];
    const float* W1 = (const float*)d_in[2];
    const float* b1 = (const float*)d_in[3];
    const float* W2 = (const float*)d_in[4];
    const float* b2 = (const float*)d_in[5];
    float* out = (float*)d_out;
    (void)in_sizes; (void)n_in; (void)out_size; (void)d_ws; (void)ws_size;

    ode_mfma6<<<dim3(Bsz / ROWS), dim3(NT), 0, stream>>>(z0, t, W1, b1, W2, b2, out);
}